// Round 2
// baseline (45.113 us; speedup 1.0000x reference)
//
#include <hip/hip_runtime.h>
#include <stdint.h>

#define BB      512
#define NCROPS  5
#define TT      8192
#define THREADS 256

// Order-preserving f32 -> u32 transform (ascending)
__device__ __forceinline__ uint32_t f2ord(float f) {
    uint32_t b = __float_as_uint(f);
    return (b & 0x80000000u) ? ~b : (b | 0x80000000u);
}
__device__ __forceinline__ float ord2f(uint32_t u) {
    uint32_t b = (u & 0x80000000u) ? (u & 0x7FFFFFFFu) : ~u;
    return __uint_as_float(b);
}

// ---------------------------------------------------------------------------
// Kernel 1: crop-mean + mask + order-key, full-BW streaming pass.
// grid = 1024 blocks x 256 thr; each block does half a row (1024 float4).
// ---------------------------------------------------------------------------
__global__ __launch_bounds__(256) void mean_keys(
    const float* __restrict__ scores, const int* __restrict__ seqlen,
    uint32_t* __restrict__ keys)
{
    const int tid  = threadIdx.x;
    const int b    = blockIdx.x >> 1;
    const int half = blockIdx.x & 1;
    const int sl   = seqlen[b];

    const float* base = scores + (size_t)b * NCROPS * TT;
    uint4* kout = reinterpret_cast<uint4*>(keys + (size_t)b * TT);

    #pragma unroll
    for (int j = 0; j < 4; ++j) {
        const int t4 = half * 1024 + tid + j * 256;
        float4 a = *reinterpret_cast<const float4*>(base + 4 * t4);
        #pragma unroll
        for (int c = 1; c < NCROPS; ++c) {
            const float4 v = *reinterpret_cast<const float4*>(base + (size_t)c * TT + 4 * t4);
            a.x += v.x; a.y += v.y; a.z += v.z; a.w += v.w;
        }
        const int t0 = 4 * t4;
        uint4 kv;
        kv.x = (t0 + 0 < sl) ? f2ord(a.x * 0.2f) : 0u;
        kv.y = (t0 + 1 < sl) ? f2ord(a.y * 0.2f) : 0u;
        kv.z = (t0 + 2 < sl) ? f2ord(a.z * 0.2f) : 0u;
        kv.w = (t0 + 3 < sl) ? f2ord(a.w * 0.2f) : 0u;
        kout[t4] = kv;
    }
}

// ---------------------------------------------------------------------------
// Kernel 2: per-row k-th-largest selection + BCE term.
// Keys held in 8 NAMED uint4 registers (32 values/thread).
// ---------------------------------------------------------------------------
#define FOR8(OP) OP(u0) OP(u1) OP(u2) OP(u3) OP(u4) OP(u5) OP(u6) OP(u7)

__global__ __launch_bounds__(THREADS) void select_loss(
    const uint32_t* __restrict__ keys, const int* __restrict__ label,
    const int* __restrict__ seqlen, float* __restrict__ row_loss)
{
    const int b    = blockIdx.x;
    const int tid  = threadIdx.x;
    const int lane = tid & 63;
    const int wave = tid >> 6;

    const int sl = seqlen[b];
    const int lb = label[b];
    const int k  = (lb == 0) ? 1 : (sl / 16 + 1);   // 1 <= k <= sl

    const uint4* kr = reinterpret_cast<const uint4*>(keys + (size_t)b * TT);
    uint4 u0 = kr[tid + 0 * 256];
    uint4 u1 = kr[tid + 1 * 256];
    uint4 u2 = kr[tid + 2 * 256];
    uint4 u3 = kr[tid + 3 * 256];
    uint4 u4 = kr[tid + 4 * 256];
    uint4 u5 = kr[tid + 5 * 256];
    uint4 u6 = kr[tid + 6 * 256];
    uint4 u7 = kr[tid + 7 * 256];

    __shared__ uint32_t s_m[4];
    __shared__ int      s_w[4];
    __shared__ float    s_s[4];
    __shared__ int      s_c[4];

    // ---- row max (1 reduce round) ----
    uint32_t mx = 0u;
    #define MAXOP(V) mx = max(mx, max(max(V.x, V.y), max(V.z, V.w)));
    FOR8(MAXOP)
    #pragma unroll
    for (int off = 32; off; off >>= 1) {
        const uint32_t o = (uint32_t)__shfl_down((int)mx, off);
        mx = max(mx, o);
    }
    if (lane == 0) s_m[wave] = mx;
    __syncthreads();
    const uint32_t rowmax = max(max(s_m[0], s_m[1]), max(s_m[2], s_m[3]));

    uint32_t kth;
    if (k == 1) {
        kth = rowmax;               // label==0 fast path: top-1 == max
    } else {
        // binary search on key bits: invariant cnt_ge(lo) >= k, answer in [lo,hi]
        uint32_t lo = 0u, hi = rowmax;
        while (lo < hi) {
            const uint32_t d   = hi - lo;
            const uint32_t mid = lo + (d >> 1) + (d & 1u);   // upper mid
            int c = 0;
            #define CNTOP(V) c += (int)(V.x >= mid) + (int)(V.y >= mid) + (int)(V.z >= mid) + (int)(V.w >= mid);
            FOR8(CNTOP)
            #pragma unroll
            for (int off = 32; off; off >>= 1) c += __shfl_down(c, off);
            if (lane == 0) s_w[wave] = c;
            __syncthreads();
            const int total = s_w[0] + s_w[1] + s_w[2] + s_w[3];
            if (total >= k) lo = mid; else hi = mid - 1;
            __syncthreads();
        }
        kth = lo;
    }

    // ---- sum and count of elements strictly greater than kth ----
    float sg = 0.f;
    int   cg = 0;
    #define SUMOP(V) \
        if (V.x > kth) { sg += ord2f(V.x); cg++; } \
        if (V.y > kth) { sg += ord2f(V.y); cg++; } \
        if (V.z > kth) { sg += ord2f(V.z); cg++; } \
        if (V.w > kth) { sg += ord2f(V.w); cg++; }
    FOR8(SUMOP)
    #pragma unroll
    for (int off = 32; off; off >>= 1) {
        sg += __shfl_down(sg, off);
        cg += __shfl_down(cg, off);
    }
    if (lane == 0) { s_s[wave] = sg; s_c[wave] = cg; }
    __syncthreads();

    if (tid == 0) {
        const float sum_g = s_s[0] + s_s[1] + s_s[2] + s_s[3];
        const int   cnt_g = s_c[0] + s_c[1] + s_c[2] + s_c[3];
        const float kf    = ord2f(kth);
        const float topk  = sum_g + (float)(k - cnt_g) * kf;
        const float v     = topk / (float)k;
        const float y     = (float)lb;
        const float la    = fmaxf(v, 0.f) + log1pf(expf(-fabsf(v)));
        row_loss[b] = la - v * y;
    }
}

// ---------------------------------------------------------------------------
// Fallback fused kernel (used only if ws is too small for the key buffer).
// ---------------------------------------------------------------------------
__global__ __launch_bounds__(THREADS) void topk_loss_rows(
    const float* __restrict__ scores, const int* __restrict__ label,
    const int* __restrict__ seqlen, float* __restrict__ row_loss)
{
    const int b    = blockIdx.x;
    const int tid  = threadIdx.x;
    const int lane = tid & 63;
    const int wave = tid >> 6;

    const int sl = seqlen[b];
    const int lb = label[b];
    const int k  = (lb == 0) ? 1 : (sl / 16 + 1);

    const float* base = scores + (size_t)b * NCROPS * TT;
    uint4 u0, u1, u2, u3, u4, u5, u6, u7;
    uint4* uptr[8] = {&u0,&u1,&u2,&u3,&u4,&u5,&u6,&u7};
    #pragma unroll
    for (int j = 0; j < 8; ++j) {
        const int t4 = tid + j * 256;
        float4 a = *reinterpret_cast<const float4*>(base + 4 * t4);
        #pragma unroll
        for (int c = 1; c < NCROPS; ++c) {
            const float4 v = *reinterpret_cast<const float4*>(base + (size_t)c * TT + 4 * t4);
            a.x += v.x; a.y += v.y; a.z += v.z; a.w += v.w;
        }
        const int t0 = 4 * t4;
        uint4 kv;
        kv.x = (t0 + 0 < sl) ? f2ord(a.x * 0.2f) : 0u;
        kv.y = (t0 + 1 < sl) ? f2ord(a.y * 0.2f) : 0u;
        kv.z = (t0 + 2 < sl) ? f2ord(a.z * 0.2f) : 0u;
        kv.w = (t0 + 3 < sl) ? f2ord(a.w * 0.2f) : 0u;
        *uptr[j] = kv;
    }

    __shared__ uint32_t s_m[4];
    __shared__ int      s_w[4];
    __shared__ float    s_s[4];
    __shared__ int      s_c[4];

    uint32_t mx = 0u;
    FOR8(MAXOP)
    #pragma unroll
    for (int off = 32; off; off >>= 1) {
        const uint32_t o = (uint32_t)__shfl_down((int)mx, off);
        mx = max(mx, o);
    }
    if (lane == 0) s_m[wave] = mx;
    __syncthreads();
    const uint32_t rowmax = max(max(s_m[0], s_m[1]), max(s_m[2], s_m[3]));

    uint32_t kth;
    if (k == 1) {
        kth = rowmax;
    } else {
        uint32_t lo = 0u, hi = rowmax;
        while (lo < hi) {
            const uint32_t d   = hi - lo;
            const uint32_t mid = lo + (d >> 1) + (d & 1u);
            int c = 0;
            FOR8(CNTOP)
            #pragma unroll
            for (int off = 32; off; off >>= 1) c += __shfl_down(c, off);
            if (lane == 0) s_w[wave] = c;
            __syncthreads();
            const int total = s_w[0] + s_w[1] + s_w[2] + s_w[3];
            if (total >= k) lo = mid; else hi = mid - 1;
            __syncthreads();
        }
        kth = lo;
    }

    float sg = 0.f;
    int   cg = 0;
    FOR8(SUMOP)
    #pragma unroll
    for (int off = 32; off; off >>= 1) {
        sg += __shfl_down(sg, off);
        cg += __shfl_down(cg, off);
    }
    if (lane == 0) { s_s[wave] = sg; s_c[wave] = cg; }
    __syncthreads();

    if (tid == 0) {
        const float sum_g = s_s[0] + s_s[1] + s_s[2] + s_s[3];
        const int   cnt_g = s_c[0] + s_c[1] + s_c[2] + s_c[3];
        const float kf    = ord2f(kth);
        const float topk  = sum_g + (float)(k - cnt_g) * kf;
        const float v     = topk / (float)k;
        const float y     = (float)lb;
        const float la    = fmaxf(v, 0.f) + log1pf(expf(-fabsf(v)));
        row_loss[b] = la - v * y;
    }
}

__global__ __launch_bounds__(256) void reduce_loss(
    const float* __restrict__ row_loss, float* __restrict__ out)
{
    const int tid = threadIdx.x;
    float v = row_loss[tid] + row_loss[tid + 256];
    #pragma unroll
    for (int off = 32; off; off >>= 1) v += __shfl_down(v, off);
    __shared__ float s[4];
    if ((tid & 63) == 0) s[tid >> 6] = v;
    __syncthreads();
    if (tid == 0) out[0] = (s[0] + s[1] + s[2] + s[3]) * (1.0f / 512.0f);
}

extern "C" void kernel_launch(void* const* d_in, const int* in_sizes, int n_in,
                              void* d_out, int out_size, void* d_ws, size_t ws_size,
                              hipStream_t stream) {
    const float* scores = (const float*)d_in[0];
    const int*   label  = (const int*)d_in[1];
    const int*   seqlen = (const int*)d_in[2];
    float* out = (float*)d_out;

    const size_t keys_bytes = (size_t)BB * TT * sizeof(uint32_t);   // 16.8 MB
    if (ws_size >= keys_bytes + 4096) {
        uint32_t* keys   = (uint32_t*)d_ws;
        float* row_loss  = (float*)((char*)d_ws + keys_bytes);
        mean_keys<<<BB * 2, 256, 0, stream>>>(scores, seqlen, keys);
        select_loss<<<BB, THREADS, 0, stream>>>(keys, label, seqlen, row_loss);
        reduce_loss<<<1, 256, 0, stream>>>(row_loss, out);
    } else {
        float* row_loss = (float*)d_ws;   // 512 floats
        topk_loss_rows<<<BB, THREADS, 0, stream>>>(scores, label, seqlen, row_loss);
        reduce_loss<<<1, 256, 0, stream>>>(row_loss, out);
    }
}

// Round 3
// 35.392 us; speedup vs baseline: 1.2747x; 1.2747x over previous
//
#include <hip/hip_runtime.h>
#include <stdint.h>

#define BB      512
#define NCROPS  5
#define TT      8192
#define THREADS 512
#define WAVES   (THREADS / 64)   // 8

// Order-preserving f32 -> u32 transform (ascending)
__device__ __forceinline__ uint32_t f2ord(float f) {
    uint32_t b = __float_as_uint(f);
    return (b & 0x80000000u) ? ~b : (b | 0x80000000u);
}
__device__ __forceinline__ float ord2f(uint32_t u) {
    uint32_t b = (u & 0x80000000u) ? (u & 0x7FFFFFFFu) : ~u;
    return __uint_as_float(b);
}

#define FOR4(OP) OP(u0) OP(u1) OP(u2) OP(u3)

__global__ __launch_bounds__(THREADS, 4) void topk_loss_rows(
    const float* __restrict__ scores, const int* __restrict__ label,
    const int* __restrict__ seqlen, float* __restrict__ row_loss)
{
    const int b    = blockIdx.x;
    const int tid  = threadIdx.x;
    const int lane = tid & 63;
    const int wave = tid >> 6;

    const int sl = seqlen[b];
    const int lb = label[b];
    const int k  = (lb == 0) ? 1 : (sl / 16 + 1);   // 1 <= k <= sl

    // ---- load + crop-mean + mask -> order keys in 4 named uint4 regs ----
    const float* base = scores + (size_t)b * NCROPS * TT;
    uint4 u0, u1, u2, u3;
    #define LOADJ(DST, J) { \
        const int t4 = tid + (J) * THREADS; \
        float4 a       = *reinterpret_cast<const float4*>(base + 4 * t4); \
        const float4 v1 = *reinterpret_cast<const float4*>(base + 1 * TT + 4 * t4); \
        const float4 v2 = *reinterpret_cast<const float4*>(base + 2 * TT + 4 * t4); \
        const float4 v3 = *reinterpret_cast<const float4*>(base + 3 * TT + 4 * t4); \
        const float4 v4 = *reinterpret_cast<const float4*>(base + 4 * TT + 4 * t4); \
        a.x = (a.x + v1.x + v2.x + v3.x + v4.x) * 0.2f; \
        a.y = (a.y + v1.y + v2.y + v3.y + v4.y) * 0.2f; \
        a.z = (a.z + v1.z + v2.z + v3.z + v4.z) * 0.2f; \
        a.w = (a.w + v1.w + v2.w + v3.w + v4.w) * 0.2f; \
        const int t0 = 4 * t4; \
        DST.x = (t0 + 0 < sl) ? f2ord(a.x) : 0u; \
        DST.y = (t0 + 1 < sl) ? f2ord(a.y) : 0u; \
        DST.z = (t0 + 2 < sl) ? f2ord(a.z) : 0u; \
        DST.w = (t0 + 3 < sl) ? f2ord(a.w) : 0u; }
    LOADJ(u0, 0) LOADJ(u1, 1) LOADJ(u2, 2) LOADJ(u3, 3)

    __shared__ int      s_w[2][WAVES];
    __shared__ uint32_t s_m[WAVES];
    __shared__ float    s_s[WAVES];
    __shared__ int      s_c[WAVES];

    // ---- row max (1 reduce round) ----
    uint32_t mx = 0u;
    #define MAXOP(V) mx = max(mx, max(max(V.x, V.y), max(V.z, V.w)));
    FOR4(MAXOP)
    #pragma unroll
    for (int off = 32; off; off >>= 1) {
        const uint32_t o = (uint32_t)__shfl_down((int)mx, off);
        mx = max(mx, o);
    }
    if (lane == 0) s_m[wave] = mx;
    __syncthreads();
    uint32_t rowmax = s_m[0];
    #pragma unroll
    for (int w = 1; w < WAVES; ++w) rowmax = max(rowmax, s_m[w]);

    // ---- find threshold: k-th largest key (binary search on bits) ----
    uint32_t thr;
    if (k == 1) {
        thr = rowmax;                       // label==0 fast path
    } else {
        uint32_t lo = 0u, hi = rowmax;      // invariant: cnt_ge(lo) >= k
        int r = 0;
        bool found = false;
        uint32_t fmid = 0u;
        while (lo < hi) {
            const uint32_t d   = hi - lo;
            const uint32_t mid = lo + (d >> 1) + (d & 1u);   // upper mid
            int c = 0;
            #define CNTOP(V) c += (int)(V.x >= mid) + (int)(V.y >= mid) + (int)(V.z >= mid) + (int)(V.w >= mid);
            FOR4(CNTOP)
            #pragma unroll
            for (int off = 32; off; off >>= 1) c += __shfl_down(c, off);
            if (lane == 0) s_w[r & 1][wave] = c;
            __syncthreads();
            int total = 0;
            #pragma unroll
            for (int w = 0; w < WAVES; ++w) total += s_w[r & 1][w];
            if (total == k) { fmid = mid; found = true; break; }   // uniform
            if (total >= k) lo = mid; else hi = mid - 1;
            ++r;
        }
        thr = found ? fmid : lo;
    }

    // ---- unified epilogue: S_ge = sum(u >= thr), C_ge = count(u >= thr)
    //      topk = S_ge - (C_ge - k) * val(thr)
    //  (covers: exact-hit C_ge==k; converged thr==kth element; k==1 thr=rowmax)
    float sg = 0.f;
    int   cg = 0;
    #define SUMOP(V) \
        if (V.x >= thr) { sg += ord2f(V.x); cg++; } \
        if (V.y >= thr) { sg += ord2f(V.y); cg++; } \
        if (V.z >= thr) { sg += ord2f(V.z); cg++; } \
        if (V.w >= thr) { sg += ord2f(V.w); cg++; }
    FOR4(SUMOP)
    #pragma unroll
    for (int off = 32; off; off >>= 1) {
        sg += __shfl_down(sg, off);
        cg += __shfl_down(cg, off);
    }
    if (lane == 0) { s_s[wave] = sg; s_c[wave] = cg; }
    __syncthreads();

    if (tid == 0) {
        float S = 0.f; int C = 0;
        #pragma unroll
        for (int w = 0; w < WAVES; ++w) { S += s_s[w]; C += s_c[w]; }
        const float kf   = ord2f(thr);
        const float topk = S - (float)(C - k) * kf;
        const float v    = topk / (float)k;
        const float y    = (float)lb;
        const float la   = fmaxf(v, 0.f) + log1pf(expf(-fabsf(v)));   // logaddexp(0,v)
        row_loss[b] = la - v * y;
    }
}

__global__ __launch_bounds__(256) void reduce_loss(
    const float* __restrict__ row_loss, float* __restrict__ out)
{
    const int tid = threadIdx.x;
    float v = row_loss[tid] + row_loss[tid + 256];
    #pragma unroll
    for (int off = 32; off; off >>= 1) v += __shfl_down(v, off);
    __shared__ float s[4];
    if ((tid & 63) == 0) s[tid >> 6] = v;
    __syncthreads();
    if (tid == 0) out[0] = (s[0] + s[1] + s[2] + s[3]) * (1.0f / 512.0f);
}

extern "C" void kernel_launch(void* const* d_in, const int* in_sizes, int n_in,
                              void* d_out, int out_size, void* d_ws, size_t ws_size,
                              hipStream_t stream) {
    const float* scores = (const float*)d_in[0];
    const int*   label  = (const int*)d_in[1];
    const int*   seqlen = (const int*)d_in[2];
    float* out      = (float*)d_out;
    float* row_loss = (float*)d_ws;   // 512 floats

    topk_loss_rows<<<BB, THREADS, 0, stream>>>(scores, label, seqlen, row_loss);
    reduce_loss<<<1, 256, 0, stream>>>(row_loss, out);
}

// Round 4
// 22.116 us; speedup vs baseline: 2.0398x; 1.6003x over previous
//
#include <hip/hip_runtime.h>
#include <stdint.h>

#define BB      512
#define NCROPS  5
#define TT      8192
#define THREADS 512
#define WAVES   8

// Order-preserving f32 -> u32 transform (ascending).
// Note: every real float maps to a key > 0, so 0u is a safe "masked" sentinel.
__device__ __forceinline__ uint32_t f2ord(float f) {
    uint32_t b = __float_as_uint(f);
    return (b & 0x80000000u) ? ~b : (b | 0x80000000u);
}
__device__ __forceinline__ float ord2f(uint32_t u) {
    uint32_t b = (u & 0x80000000u) ? (u & 0x7FFFFFFFu) : ~u;
    return __uint_as_float(b);
}

#define FOR4(OP) OP(u0) OP(u1) OP(u2) OP(u3)

__global__ __launch_bounds__(THREADS, 4) void topk_loss_rows(
    const float* __restrict__ scores, const int* __restrict__ label,
    const int* __restrict__ seqlen, float* __restrict__ row_loss)
{
    const int b    = blockIdx.x;
    const int tid  = threadIdx.x;
    const int lane = tid & 63;
    const int wave = tid >> 6;

    const int sl = seqlen[b];
    const int lb = label[b];
    const int k  = (lb == 0) ? 1 : (sl / 16 + 1);   // 1 <= k <= sl

    __shared__ uint32_t hist[2][WAVES][256];        // 16 KB, double-buffered
    __shared__ uint32_t bc_p, bc_k;
    __shared__ uint32_t s_m[WAVES];
    __shared__ float    s_s[WAVES];
    __shared__ int      s_c[WAVES];

    // ---- issue ALL conditional loads first (keeps 20 float4 in flight) ----
    const float* base = scores + (size_t)b * NCROPS * TT;
    #define LOADJ(A0,A1,A2,A3,A4, J, PRED) \
        const bool PRED = (4 * (tid + (J) * THREADS) < sl); \
        float4 A0, A1, A2, A3, A4; \
        if (PRED) { \
            const int t4 = tid + (J) * THREADS; \
            A0 = *reinterpret_cast<const float4*>(base + 0 * TT + 4 * t4); \
            A1 = *reinterpret_cast<const float4*>(base + 1 * TT + 4 * t4); \
            A2 = *reinterpret_cast<const float4*>(base + 2 * TT + 4 * t4); \
            A3 = *reinterpret_cast<const float4*>(base + 3 * TT + 4 * t4); \
            A4 = *reinterpret_cast<const float4*>(base + 4 * TT + 4 * t4); \
        }
    LOADJ(a0,b0,c0,d0,e0, 0, p0)
    LOADJ(a1,b1,c1,d1,e1, 1, p1)
    LOADJ(a2,b2,c2,d2,e2, 2, p2)
    LOADJ(a3,b3,c3,d3,e3, 3, p3)

    // zero histogram buffer 0 while loads are in flight
    {
        uint32_t* hz = &hist[0][0][0];
        #pragma unroll
        for (int i = 0; i < 4; ++i) hz[tid + i * THREADS] = 0u;
    }
    __syncthreads();

    // ---- crop-mean + mask -> order keys in 4 named uint4 regs ----
    uint4 u0, u1, u2, u3;
    #define KEYJ(DST, A0,A1,A2,A3,A4, J, PRED) \
        if (PRED) { \
            const int t0 = 4 * (tid + (J) * THREADS); \
            float4 a; \
            a.x = (A0.x + A1.x + A2.x + A3.x + A4.x) * 0.2f; \
            a.y = (A0.y + A1.y + A2.y + A3.y + A4.y) * 0.2f; \
            a.z = (A0.z + A1.z + A2.z + A3.z + A4.z) * 0.2f; \
            a.w = (A0.w + A1.w + A2.w + A3.w + A4.w) * 0.2f; \
            DST.x = f2ord(a.x); \
            DST.y = (t0 + 1 < sl) ? f2ord(a.y) : 0u; \
            DST.z = (t0 + 2 < sl) ? f2ord(a.z) : 0u; \
            DST.w = (t0 + 3 < sl) ? f2ord(a.w) : 0u; \
        } else { \
            DST.x = 0u; DST.y = 0u; DST.z = 0u; DST.w = 0u; \
        }
    KEYJ(u0, a0,b0,c0,d0,e0, 0, p0)
    KEYJ(u1, a1,b1,c1,d1,e1, 1, p1)
    KEYJ(u2, a2,b2,c2,d2,e2, 2, p2)
    KEYJ(u3, a3,b3,c3,d3,e3, 3, p3)

    uint32_t thr;
    if (k == 1) {
        // ---- label==0 fast path: threshold = row max ----
        uint32_t mx = 0u;
        #define MAXOP(V) mx = max(mx, max(max(V.x, V.y), max(V.z, V.w)));
        FOR4(MAXOP)
        #pragma unroll
        for (int off = 32; off; off >>= 1) {
            const uint32_t o = (uint32_t)__shfl_down((int)mx, off);
            mx = max(mx, o);
        }
        if (lane == 0) s_m[wave] = mx;
        __syncthreads();
        uint32_t rowmax = s_m[0];
        #pragma unroll
        for (int w = 1; w < WAVES; ++w) rowmax = max(rowmax, s_m[w]);
        thr = rowmax;
    } else {
        // ---- MSB-first radix select, 4 rounds x 8 bits ----
        uint32_t p = 0u, kr = (uint32_t)k;
        #pragma unroll
        for (int r = 0; r < 4; ++r) {
            uint32_t* h = &hist[r & 1][wave][0];
            if (r == 0) {
                #define H0(X)  if ((X) != 0u) atomicAdd(&h[(X) >> 24], 1u);
                #define H0V(V) H0(V.x) H0(V.y) H0(V.z) H0(V.w)
                FOR4(H0V)
            } else {
                const int shp = 32 - 8 * r;   // prefix shift
                const int shd = shp - 8;      // digit shift
                #define HR(X)  if ((X) != 0u && ((X) >> shp) == p) atomicAdd(&h[((X) >> shd) & 255u], 1u);
                #define HRV(V) HR(V.x) HR(V.y) HR(V.z) HR(V.w)
                FOR4(HRV)
            }
            __syncthreads();
            if (wave == 0) {
                // combine 8 wave-hists for 4 bins/lane, suffix-scan, pick digit
                uint32_t t0s = 0u, t1s = 0u, t2s = 0u, t3s = 0u;
                #pragma unroll
                for (int w = 0; w < WAVES; ++w) {
                    const uint32_t* hw = &hist[r & 1][w][0];
                    t0s += hw[4 * lane + 0];
                    t1s += hw[4 * lane + 1];
                    t2s += hw[4 * lane + 2];
                    t3s += hw[4 * lane + 3];
                }
                const uint32_t s = t0s + t1s + t2s + t3s;
                uint32_t suf = s;                         // inclusive suffix sum
                #pragma unroll
                for (int off = 1; off < 64; off <<= 1) {
                    const uint32_t v = (uint32_t)__shfl_down((int)suf, off);
                    if (lane + off < 64) suf += v;
                }
                const uint32_t E  = suf - s;              // sum over lanes > l
                const uint32_t T3 = E  + t3s;             // T(c) = cnt(keys >= bin c)
                const uint32_t T2 = T3 + t2s;
                const uint32_t T1 = T2 + t1s;
                const uint32_t T0 = T1 + t0s;
                const unsigned long long bal = __ballot(T0 >= kr);
                const int L = 63 - __clzll(bal);          // highest lane w/ T >= kr
                if (lane == L) {
                    uint32_t j, Tj, tj;
                    if      (T3 >= kr) { j = 3u; Tj = T3; tj = t3s; }
                    else if (T2 >= kr) { j = 2u; Tj = T2; tj = t2s; }
                    else if (T1 >= kr) { j = 1u; Tj = T1; tj = t1s; }
                    else               { j = 0u; Tj = T0; tj = t0s; }
                    bc_p = (p << 8) | (uint32_t)(4 * lane) | j;
                    bc_k = kr - (Tj - tj);                // rank within chosen bin
                }
            } else if (r < 3) {
                // zero the other buffer for the next round (overlaps the scan)
                uint32_t* hz = &hist[(r + 1) & 1][0][0];
                for (int i = tid - 64; i < 2048; i += (THREADS - 64)) hz[i] = 0u;
            }
            __syncthreads();
            p  = bc_p;
            kr = bc_k;
        }
        thr = p;   // exact bit pattern of the k-th largest key
    }

    // ---- unified epilogue: topk = sum(u>=thr) - (cnt(u>=thr)-k)*val(thr) ----
    float sg = 0.f;
    int   cg = 0;
    #define SUMOP(V) \
        if (V.x >= thr) { sg += ord2f(V.x); cg++; } \
        if (V.y >= thr) { sg += ord2f(V.y); cg++; } \
        if (V.z >= thr) { sg += ord2f(V.z); cg++; } \
        if (V.w >= thr) { sg += ord2f(V.w); cg++; }
    FOR4(SUMOP)
    #pragma unroll
    for (int off = 32; off; off >>= 1) {
        sg += __shfl_down(sg, off);
        cg += __shfl_down(cg, off);
    }
    if (lane == 0) { s_s[wave] = sg; s_c[wave] = cg; }
    __syncthreads();

    if (tid == 0) {
        float S = 0.f; int C = 0;
        #pragma unroll
        for (int w = 0; w < WAVES; ++w) { S += s_s[w]; C += s_c[w]; }
        const float kf   = ord2f(thr);
        const float topk = S - (float)(C - k) * kf;
        const float v    = topk / (float)k;
        const float y    = (float)lb;
        const float la   = fmaxf(v, 0.f) + log1pf(expf(-fabsf(v)));  // logaddexp(0,v)
        row_loss[b] = la - v * y;
    }
}

__global__ __launch_bounds__(256) void reduce_loss(
    const float* __restrict__ row_loss, float* __restrict__ out)
{
    const int tid = threadIdx.x;
    float v = row_loss[tid] + row_loss[tid + 256];
    #pragma unroll
    for (int off = 32; off; off >>= 1) v += __shfl_down(v, off);
    __shared__ float s[4];
    if ((tid & 63) == 0) s[tid >> 6] = v;
    __syncthreads();
    if (tid == 0) out[0] = (s[0] + s[1] + s[2] + s[3]) * (1.0f / 512.0f);
}

extern "C" void kernel_launch(void* const* d_in, const int* in_sizes, int n_in,
                              void* d_out, int out_size, void* d_ws, size_t ws_size,
                              hipStream_t stream) {
    const float* scores = (const float*)d_in[0];
    const int*   label  = (const int*)d_in[1];
    const int*   seqlen = (const int*)d_in[2];
    float* out      = (float*)d_out;
    float* row_loss = (float*)d_ws;   // 512 floats

    topk_loss_rows<<<BB, THREADS, 0, stream>>>(scores, label, seqlen, row_loss);
    reduce_loss<<<1, 256, 0, stream>>>(row_loss, out);
}